// Round 2
// baseline (2734.500 us; speedup 1.0000x reference)
//
#include <hip/hip_runtime.h>
#include <hip/hip_bf16.h>
#include <cstdint>

typedef __attribute__((ext_vector_type(8))) short bf16x8;
typedef __attribute__((ext_vector_type(4))) float f32x4;

#define V_ 32000
#define E_ 512
#define H_ 1024
#define B_ 32
#define S_ 128

// ---- async global->LDS, 16B per lane (dest = wave-uniform base + lane*16) ----
typedef __attribute__((address_space(1))) unsigned int* gas1_t;
typedef __attribute__((address_space(3))) unsigned int* las3_t;
__device__ __forceinline__ void load_lds16(const void* g, void* l) {
  __builtin_amdgcn_global_load_lds((gas1_t)g, (las3_t)l, 16, 0, 0);
}

// ---- transpose + f32->bf16 : src[R][C] -> dst[C][R] ----
__global__ __launch_bounds__(256) void transpose_f32_bf16(
    const float* __restrict__ src, __hip_bfloat16* __restrict__ dst, int R, int C) {
  __shared__ float tile[32][33];
  const int c0 = blockIdx.x << 5, r0 = blockIdx.y << 5;
  const int tx = threadIdx.x & 31, ty = threadIdx.x >> 5;  // ty 0..7
#pragma unroll
  for (int i = 0; i < 32; i += 8)
    tile[ty + i][tx] = src[(size_t)(r0 + ty + i) * C + (c0 + tx)];
  __syncthreads();
#pragma unroll
  for (int i = 0; i < 32; i += 8)
    dst[(size_t)(c0 + ty + i) * R + (r0 + tx)] = __float2bfloat16(tile[tx][ty + i]);
}

// ---- embedding gather -> bf16, rows ordered r = t*32 + b ----
__global__ __launch_bounds__(256) void gather_embed(
    const int* __restrict__ tokens, const float* __restrict__ emb,
    __hip_bfloat16* __restrict__ Xg) {
  const int r = blockIdx.x;          // 0..4095
  const int t = r >> 5, b = r & 31;
  const int tok = tokens[b * S_ + t];
  const float* e = emb + (size_t)tok * E_;
  __hip_bfloat16* o = Xg + (size_t)r * E_;
  for (int k = threadIdx.x; k < E_; k += 256) o[k] = __float2bfloat16(e[k]);
}

// ---- pre-arrange a [1024][1024] f32 weight (row=k, col=j) into MFMA B-fragment
//      linear bf16 layout: F[g:64][kb:32][lane:64][e:8] = W[kb*32+(lane>>4)*8+e][g*16+(lane&15)]
__global__ __launch_bounds__(256) void make_frag_w(
    const float* __restrict__ W, __hip_bfloat16* __restrict__ F) {
  const int idx = blockIdx.x * 256 + threadIdx.x;  // 64*32*64 = 131072 total
  const int lane = idx & 63, kb = (idx >> 6) & 31, g = idx >> 11;
  const int j = (g << 4) + (lane & 15);
  const int kbase = (kb << 5) + ((lane >> 4) << 3);
  __hip_bfloat16* o = F + (size_t)idx * 8;
#pragma unroll
  for (int e = 0; e < 8; ++e) o[e] = __float2bfloat16(W[(size_t)(kbase + e) * H_ + j]);
}

// ---- m97-style bf16 MFMA GEMM: C[M][N] = A[M][K] * Bt[N][K]^T + bias ----
__global__ __launch_bounds__(256) void gemm_bf16_tn(
    const __hip_bfloat16* __restrict__ A,   // [M][K] row-major
    const __hip_bfloat16* __restrict__ Bt,  // [N][K] row-major
    const float* __restrict__ bias,         // [N]
    float* __restrict__ C,                  // [M][N]
    int M, int N, int K) {
  __shared__ __hip_bfloat16 ldsA[128 * 64];
  __shared__ __hip_bfloat16 ldsB[128 * 64];
  const int m0 = blockIdx.y << 7, n0 = blockIdx.x << 7;
  const int tid = threadIdx.x, wave = tid >> 6, lane = tid & 63;
  const int wr = wave >> 1, wc = wave & 1;
  f32x4 acc[4][4];
#pragma unroll
  for (int i = 0; i < 4; ++i)
#pragma unroll
    for (int jj = 0; jj < 4; ++jj) acc[i][jj] = (f32x4){0.f, 0.f, 0.f, 0.f};

  for (int k0 = 0; k0 < K; k0 += 64) {
#pragma unroll
    for (int i = 0; i < 4; ++i) {
      const int c = i * 4 + wave;          // chunk 0..15 (1KB each)
      const int idx = (c << 6) + lane;     // 0..1023
      const int row = idx >> 3, kk = (idx & 7) << 3;
      load_lds16(A + (size_t)(m0 + row) * K + (k0 + kk), ldsA + c * 512);
      load_lds16(Bt + (size_t)(n0 + row) * K + (k0 + kk), ldsB + c * 512);
    }
    __syncthreads();
#pragma unroll
    for (int ks = 0; ks < 2; ++ks) {
      bf16x8 af[4], bfr[4];
#pragma unroll
      for (int mi = 0; mi < 4; ++mi)
        af[mi] = *(const bf16x8*)(ldsA + (((wr << 6) + (mi << 4) + (lane & 15)) << 6) +
                                  (ks << 5) + ((lane >> 4) << 3));
#pragma unroll
      for (int ni = 0; ni < 4; ++ni)
        bfr[ni] = *(const bf16x8*)(ldsB + (((wc << 6) + (ni << 4) + (lane & 15)) << 6) +
                                   (ks << 5) + ((lane >> 4) << 3));
#pragma unroll
      for (int mi = 0; mi < 4; ++mi)
#pragma unroll
        for (int ni = 0; ni < 4; ++ni)
          acc[mi][ni] =
              __builtin_amdgcn_mfma_f32_16x16x32_bf16(af[mi], bfr[ni], acc[mi][ni], 0, 0, 0);
    }
    __syncthreads();
  }
#pragma unroll
  for (int mi = 0; mi < 4; ++mi) {
#pragma unroll
    for (int ni = 0; ni < 4; ++ni) {
      const int n = n0 + (wc << 6) + (ni << 4) + (lane & 15);
      const float bn = bias[n];
#pragma unroll
      for (int r = 0; r < 4; ++r) {
        const int m = m0 + (wr << 6) + (mi << 4) + ((lane >> 4) << 2) + r;
        C[(size_t)m * N + n] = acc[mi][ni][r] + bn;
      }
    }
  }
}

// ---- cooperative recurrence: 64 WGs x 256 thr, weights persistent in LDS ----
// Custom monotonic spin-barrier replaces cg::grid.sync (15.9us -> ~1-2us/step).
__global__ __launch_bounds__(256, 1) void rnn_recur(
    const __hip_bfloat16* __restrict__ U0f, const __hip_bfloat16* __restrict__ W1f,
    const __hip_bfloat16* __restrict__ U1f, const float* __restrict__ xw,  // [128][32][1024]
    const float* __restrict__ b1,
    __hip_bfloat16* __restrict__ h0buf,  // [2][32][1024]
    __hip_bfloat16* __restrict__ h1buf,  // [2][32][1024]
    __hip_bfloat16* __restrict__ Y,      // [4096][1024], row = b*128 + t
    unsigned* __restrict__ bar) {        // zeroed before launch
  __shared__ __hip_bfloat16 sm[3 * 16384];  // 96KB: U0 slab | W1 slab | U1 slab
  __hip_bfloat16* s_u0 = sm;
  __hip_bfloat16* s_w1 = sm + 16384;
  __hip_bfloat16* s_u1 = sm + 32768;
  const int g = blockIdx.x;  // column group: cols g*16 .. g*16+15
  const int tid = threadIdx.x, wave = tid >> 6, lane = tid & 63;
  const int mi = wave & 1;  // batch-frag: rows mi*16..mi*16+15

  {  // stage the 3 weight slabs (32KB each) once
    const size_t base = (size_t)g * 16384;
    const uint4* su0 = (const uint4*)(U0f + base);
    const uint4* sw1 = (const uint4*)(W1f + base);
    const uint4* su1 = (const uint4*)(U1f + base);
    uint4* d0 = (uint4*)s_u0;
    uint4* d1 = (uint4*)s_w1;
    uint4* d2 = (uint4*)s_u1;
    for (int i = tid; i < 2048; i += 256) {
      d0[i] = su0[i];
      d1[i] = sw1[i];
      d2[i] = su1[i];
    }
  }
  __syncthreads();

  const int j = (g << 4) + (lane & 15);
  const int rowbase = (mi << 4) + ((lane >> 4) << 2);
  const int arow_off = ((mi << 4) + (lane & 15)) * H_ + ((lane >> 4) << 3);

  for (int p = 0; p <= S_; ++p) {
    if (wave < 2) {
      if (p < S_) {
        const __hip_bfloat16* h0p = h0buf + (((p & 1) ^ 1) << 15);  // h0(p-1)
        const __hip_bfloat16* ar = h0p + arow_off;
        f32x4 a0 = {0.f, 0.f, 0.f, 0.f}, a1 = {0.f, 0.f, 0.f, 0.f};
#pragma unroll
        for (int kc = 0; kc < 16; ++kc) {
          bf16x8 x0 = *(const bf16x8*)(ar + (kc << 5));
          bf16x8 w0 = *(const bf16x8*)(s_u0 + (((kc << 6) + lane) << 3));
          a0 = __builtin_amdgcn_mfma_f32_16x16x32_bf16(x0, w0, a0, 0, 0, 0);
          bf16x8 x1 = *(const bf16x8*)(ar + ((kc + 16) << 5));
          bf16x8 w1 = *(const bf16x8*)(s_u0 + ((((kc + 16) << 6) + lane) << 3));
          a1 = __builtin_amdgcn_mfma_f32_16x16x32_bf16(x1, w1, a1, 0, 0, 0);
        }
        f32x4 acc = a0 + a1;
        __hip_bfloat16* hw = h0buf + ((p & 1) << 15);
        const float* xrow = xw + ((size_t)p << 15);
#pragma unroll
        for (int r = 0; r < 4; ++r) {
          const int bb = rowbase + r;
          const float v = tanhf(acc[r] + xrow[bb * H_ + j]);
          hw[bb * H_ + j] = __float2bfloat16(v);
        }
      }
    } else {
      if (p >= 1) {
        const __hip_bfloat16* h0p = h0buf + (((p & 1) ^ 1) << 15);   // h0(p-1)
        const __hip_bfloat16* h1pp = h1buf + ((p & 1) << 15);        // h1(p-2)
        const __hip_bfloat16* ar0 = h0p + arow_off;
        const __hip_bfloat16* ar1 = h1pp + arow_off;
        f32x4 a0 = {0.f, 0.f, 0.f, 0.f}, a1 = {0.f, 0.f, 0.f, 0.f};
        f32x4 a2 = {0.f, 0.f, 0.f, 0.f}, a3 = {0.f, 0.f, 0.f, 0.f};
#pragma unroll
        for (int kc = 0; kc < 16; ++kc) {
          bf16x8 xa = *(const bf16x8*)(ar0 + (kc << 5));
          bf16x8 wa = *(const bf16x8*)(s_w1 + (((kc << 6) + lane) << 3));
          a0 = __builtin_amdgcn_mfma_f32_16x16x32_bf16(xa, wa, a0, 0, 0, 0);
          bf16x8 xb = *(const bf16x8*)(ar0 + ((kc + 16) << 5));
          bf16x8 wb = *(const bf16x8*)(s_w1 + ((((kc + 16) << 6) + lane) << 3));
          a1 = __builtin_amdgcn_mfma_f32_16x16x32_bf16(xb, wb, a1, 0, 0, 0);
          bf16x8 xc = *(const bf16x8*)(ar1 + (kc << 5));
          bf16x8 wc = *(const bf16x8*)(s_u1 + (((kc << 6) + lane) << 3));
          a2 = __builtin_amdgcn_mfma_f32_16x16x32_bf16(xc, wc, a2, 0, 0, 0);
          bf16x8 xd = *(const bf16x8*)(ar1 + ((kc + 16) << 5));
          bf16x8 wd = *(const bf16x8*)(s_u1 + ((((kc + 16) << 6) + lane) << 3));
          a3 = __builtin_amdgcn_mfma_f32_16x16x32_bf16(xd, wd, a3, 0, 0, 0);
        }
        f32x4 acc = (a0 + a1) + (a2 + a3);
        const int t = p - 1;
        __hip_bfloat16* hw = h1buf + (((p - 1) & 1) << 15);
#pragma unroll
        for (int r = 0; r < 4; ++r) {
          const int bb = rowbase + r;
          const float v = tanhf(acc[r] + b1[j]);
          const __hip_bfloat16 bv = __float2bfloat16(v);
          hw[bb * H_ + j] = bv;
          Y[((size_t)bb * S_ + t) * H_ + j] = bv;
        }
      }
    }
    if (p < S_) {
      // ---- custom grid barrier: release -> arrive -> spin -> acquire ----
      __syncthreads();
      __threadfence();  // release: make h writes device-visible (wbl2)
      if (tid == 0) {
        atomicAdd(bar, 1u);
        const unsigned tgt = 64u * (unsigned)(p + 1);
        while (__hip_atomic_load(bar, __ATOMIC_RELAXED, __HIP_MEMORY_SCOPE_AGENT) < tgt) {
        }
      }
      __syncthreads();
      __threadfence();  // acquire: invalidate stale L1/L2 lines
    }
  }
}

extern "C" void kernel_launch(void* const* d_in, const int* in_sizes, int n_in, void* d_out,
                              int out_size, void* d_ws, size_t ws_size, hipStream_t stream) {
  const int* tokens = (const int*)d_in[0];
  const float* emb = (const float*)d_in[1];
  const float* W0 = (const float*)d_in[2];
  const float* U0 = (const float*)d_in[3];
  const float* b0 = (const float*)d_in[4];
  const float* W1 = (const float*)d_in[5];
  const float* U1 = (const float*)d_in[6];
  const float* b1 = (const float*)d_in[7];
  const float* Wd = (const float*)d_in[8];
  const float* bd = (const float*)d_in[9];
  float* out = (float*)d_out;

  char* ws = (char*)d_ws;
  __hip_bfloat16* Wdt = (__hip_bfloat16*)ws;  ws += (size_t)V_ * H_ * 2;       // 64MB
  __hip_bfloat16* W0t = (__hip_bfloat16*)ws;  ws += (size_t)H_ * E_ * 2;       // 1MB
  __hip_bfloat16* Xg = (__hip_bfloat16*)ws;   ws += (size_t)4096 * E_ * 2;     // 4MB
  __hip_bfloat16* U0f = (__hip_bfloat16*)ws;  ws += (size_t)H_ * H_ * 2;       // 2MB
  __hip_bfloat16* W1f = (__hip_bfloat16*)ws;  ws += (size_t)H_ * H_ * 2;       // 2MB
  __hip_bfloat16* U1f = (__hip_bfloat16*)ws;  ws += (size_t)H_ * H_ * 2;       // 2MB
  float* xw = (float*)ws;                     ws += (size_t)4096 * H_ * 4;     // 16MB
  __hip_bfloat16* h0buf = (__hip_bfloat16*)ws; ws += 2 * B_ * H_ * 2;          // 128KB
  __hip_bfloat16* h1buf = (__hip_bfloat16*)ws; ws += 2 * B_ * H_ * 2;          // 128KB
  __hip_bfloat16* Y = (__hip_bfloat16*)ws;    ws += (size_t)4096 * H_ * 2;     // 8MB
  unsigned* bar = (unsigned*)ws;              ws += 256;

  // prep
  transpose_f32_bf16<<<dim3(V_ / 32, H_ / 32), 256, 0, stream>>>(Wd, Wdt, H_, V_);
  transpose_f32_bf16<<<dim3(H_ / 32, E_ / 32), 256, 0, stream>>>(W0, W0t, E_, H_);
  gather_embed<<<4096, 256, 0, stream>>>(tokens, emb, Xg);
  make_frag_w<<<512, 256, 0, stream>>>(U0, U0f);
  make_frag_w<<<512, 256, 0, stream>>>(W1, W1f);
  make_frag_w<<<512, 256, 0, stream>>>(U1, U1f);
  hipMemsetAsync(h0buf, 0, (size_t)4 * B_ * H_ * 2, stream);  // h0buf + h1buf
  hipMemsetAsync(bar, 0, 256, stream);

  // xw = Xg @ W0 + b0   (M=4096, N=1024, K=512)
  gemm_bf16_tn<<<dim3(H_ / 128, 4096 / 128), 256, 0, stream>>>(Xg, W0t, b0, xw, 4096, H_, E_);

  // recurrence (cooperative for co-residency; custom barrier inside)
  {
    const __hip_bfloat16 *pU0f = U0f, *pW1f = W1f, *pU1f = U1f;
    const float *pxw = xw, *pb1 = b1;
    __hip_bfloat16 *ph0 = h0buf, *ph1 = h1buf, *pY = Y;
    unsigned* pbar = bar;
    void* args[] = {&pU0f, &pW1f, &pU1f, &pxw, &pb1, &ph0, &ph1, &pY, &pbar};
    hipLaunchCooperativeKernel((void*)rnn_recur, dim3(64), dim3(256), args, 0, stream);
  }

  // logits = Y @ Wd + bd   (M=4096, N=32000, K=1024)
  gemm_bf16_tn<<<dim3(V_ / 128, 4096 / 128), 256, 0, stream>>>(Y, Wdt, bd, out, 4096, V_, H_);
}

// Round 4
// 1546.184 us; speedup vs baseline: 1.7685x; 1.7685x over previous
//
#include <hip/hip_runtime.h>
#include <hip/hip_bf16.h>
#include <cstdint>

typedef __attribute__((ext_vector_type(8))) short bf16x8;
typedef __attribute__((ext_vector_type(4))) float f32x4;

#define V_ 32000
#define E_ 512
#define H_ 1024
#define B_ 32
#define S_ 128

// ---- async global->LDS, 16B per lane (dest = wave-uniform base + lane*16) ----
typedef __attribute__((address_space(1))) unsigned int* gas1_t;
typedef __attribute__((address_space(3))) unsigned int* las3_t;
__device__ __forceinline__ void load_lds16(const void* g, void* l) {
  __builtin_amdgcn_global_load_lds((gas1_t)g, (las3_t)l, 16, 0, 0);
}

// ---- coherent h-state exchange primitives ----
// load: bypass L1+L2, read at MALL/memory
__device__ __forceinline__ void ldx4_sc(bf16x8* d, const void* p) {
  asm volatile("global_load_dwordx4 %0, %1, off sc0 sc1" : "=v"(*d) : "v"(p) : "memory");
}
// store: device-scope atomic swap (no return) — executes at the coherence point,
// guaranteed visible to the sc0/sc1 loads above (plain sc stores were NOT: R3 failure).
__device__ __forceinline__ void st_swap(unsigned* p, unsigned v) {
  asm volatile("global_atomic_swap %0, %1, off sc1" :: "v"(p), "v"(v) : "memory");
}
#define WAITVM(n)                                           \
  asm volatile("s_waitcnt vmcnt(" #n ")" ::: "memory");     \
  __builtin_amdgcn_sched_barrier(0)

__device__ __forceinline__ unsigned short bfbits(float x) {
  __hip_bfloat16 b = __float2bfloat16(x);
  union { __hip_bfloat16 b; unsigned short u; } c;
  c.b = b;
  return c.u;
}

// ---- transpose + f32->bf16 : src[R][C] -> dst[C][R] ----
__global__ __launch_bounds__(256) void transpose_f32_bf16(
    const float* __restrict__ src, __hip_bfloat16* __restrict__ dst, int R, int C) {
  __shared__ float tile[32][33];
  const int c0 = blockIdx.x << 5, r0 = blockIdx.y << 5;
  const int tx = threadIdx.x & 31, ty = threadIdx.x >> 5;  // ty 0..7
#pragma unroll
  for (int i = 0; i < 32; i += 8)
    tile[ty + i][tx] = src[(size_t)(r0 + ty + i) * C + (c0 + tx)];
  __syncthreads();
#pragma unroll
  for (int i = 0; i < 32; i += 8)
    dst[(size_t)(c0 + ty + i) * R + (r0 + tx)] = __float2bfloat16(tile[tx][ty + i]);
}

// ---- embedding gather -> bf16, rows ordered r = t*32 + b ----
__global__ __launch_bounds__(256) void gather_embed(
    const int* __restrict__ tokens, const float* __restrict__ emb,
    __hip_bfloat16* __restrict__ Xg) {
  const int r = blockIdx.x;          // 0..4095
  const int t = r >> 5, b = r & 31;
  const int tok = tokens[b * S_ + t];
  const float* e = emb + (size_t)tok * E_;
  __hip_bfloat16* o = Xg + (size_t)r * E_;
  for (int k = threadIdx.x; k < E_; k += 256) o[k] = __float2bfloat16(e[k]);
}

// ---- pre-arrange a [1024][1024] f32 weight (row=k, col=j) into MFMA B-fragment
//      linear bf16 layout: F[g:64][kb:32][lane:64][e:8] = W[kb*32+(lane>>4)*8+e][g*16+(lane&15)]
__global__ __launch_bounds__(256) void make_frag_w(
    const float* __restrict__ W, __hip_bfloat16* __restrict__ F) {
  const int idx = blockIdx.x * 256 + threadIdx.x;  // 64*32*64 = 131072 total
  const int lane = idx & 63, kb = (idx >> 6) & 31, g = idx >> 11;
  const int j = (g << 4) + (lane & 15);
  const int kbase = (kb << 5) + ((lane >> 4) << 3);
  __hip_bfloat16* o = F + (size_t)idx * 8;
#pragma unroll
  for (int e = 0; e < 8; ++e) o[e] = __float2bfloat16(W[(size_t)(kbase + e) * H_ + j]);
}

// ---- m97-style bf16 MFMA GEMM: C[M][N] = A[M][K] * Bt[N][K]^T + bias ----
__global__ __launch_bounds__(256) void gemm_bf16_tn(
    const __hip_bfloat16* __restrict__ A,   // [M][K] row-major
    const __hip_bfloat16* __restrict__ Bt,  // [N][K] row-major
    const float* __restrict__ bias,         // [N]
    float* __restrict__ C,                  // [M][N]
    int M, int N, int K) {
  __shared__ __hip_bfloat16 ldsA[128 * 64];
  __shared__ __hip_bfloat16 ldsB[128 * 64];
  const int m0 = blockIdx.y << 7, n0 = blockIdx.x << 7;
  const int tid = threadIdx.x, wave = tid >> 6, lane = tid & 63;
  const int wr = wave >> 1, wc = wave & 1;
  f32x4 acc[4][4];
#pragma unroll
  for (int i = 0; i < 4; ++i)
#pragma unroll
    for (int jj = 0; jj < 4; ++jj) acc[i][jj] = (f32x4){0.f, 0.f, 0.f, 0.f};

  for (int k0 = 0; k0 < K; k0 += 64) {
#pragma unroll
    for (int i = 0; i < 4; ++i) {
      const int c = i * 4 + wave;          // chunk 0..15 (1KB each)
      const int idx = (c << 6) + lane;     // 0..1023
      const int row = idx >> 3, kk = (idx & 7) << 3;
      load_lds16(A + (size_t)(m0 + row) * K + (k0 + kk), ldsA + c * 512);
      load_lds16(Bt + (size_t)(n0 + row) * K + (k0 + kk), ldsB + c * 512);
    }
    __syncthreads();
#pragma unroll
    for (int ks = 0; ks < 2; ++ks) {
      bf16x8 af[4], bfr[4];
#pragma unroll
      for (int mi = 0; mi < 4; ++mi)
        af[mi] = *(const bf16x8*)(ldsA + (((wr << 6) + (mi << 4) + (lane & 15)) << 6) +
                                  (ks << 5) + ((lane >> 4) << 3));
#pragma unroll
      for (int ni = 0; ni < 4; ++ni)
        bfr[ni] = *(const bf16x8*)(ldsB + (((wc << 6) + (ni << 4) + (lane & 15)) << 6) +
                                   (ks << 5) + ((lane >> 4) << 3));
#pragma unroll
      for (int mi = 0; mi < 4; ++mi)
#pragma unroll
        for (int ni = 0; ni < 4; ++ni)
          acc[mi][ni] =
              __builtin_amdgcn_mfma_f32_16x16x32_bf16(af[mi], bfr[ni], acc[mi][ni], 0, 0, 0);
    }
    __syncthreads();
  }
#pragma unroll
  for (int mi = 0; mi < 4; ++mi) {
#pragma unroll
    for (int ni = 0; ni < 4; ++ni) {
      const int n = n0 + (wc << 6) + (ni << 4) + (lane & 15);
      const float bn = bias[n];
#pragma unroll
      for (int r = 0; r < 4; ++r) {
        const int m = m0 + (wr << 6) + (mi << 4) + ((lane >> 4) << 2) + r;
        C[(size_t)m * N + n] = acc[mi][ni][r] + bn;
      }
    }
  }
}

// ---- recurrence: 64 WGs x 256 thr (normal launch; 64 WGs * 96KB LDS trivially
// co-resident on 256 CUs). h-state exchange: atomic-swap stores (coherence point)
// + sc0/sc1 bypass loads. No threadfence / no L2 writeback-invalidate walks.
__global__ __launch_bounds__(256, 1) void rnn_recur(
    const __hip_bfloat16* __restrict__ U0f, const __hip_bfloat16* __restrict__ W1f,
    const __hip_bfloat16* __restrict__ U1f, const float* __restrict__ xw,  // [128][32][1024]
    const float* __restrict__ b1,
    __hip_bfloat16* __restrict__ h0buf,  // [2][32][1024]
    __hip_bfloat16* __restrict__ h1buf,  // [2][32][1024]
    __hip_bfloat16* __restrict__ Y,      // [4096][1024], row = b*128 + t
    unsigned* __restrict__ bar) {        // zeroed before launch
  __shared__ __hip_bfloat16 sm[3 * 16384];  // 96KB: U0 slab | W1 slab | U1 slab
  __hip_bfloat16* s_u0 = sm;
  __hip_bfloat16* s_w1 = sm + 16384;
  __hip_bfloat16* s_u1 = sm + 32768;
  const int g = blockIdx.x;  // column group: cols g*16 .. g*16+15
  const int tid = threadIdx.x, wave = tid >> 6, lane = tid & 63;
  const int mi = wave & 1;  // batch-frag: rows mi*16..mi*16+15

  {  // stage the 3 weight slabs (32KB each) once
    const size_t base = (size_t)g * 16384;
    const uint4* su0 = (const uint4*)(U0f + base);
    const uint4* sw1 = (const uint4*)(W1f + base);
    const uint4* su1 = (const uint4*)(U1f + base);
    uint4* d0 = (uint4*)s_u0;
    uint4* d1 = (uint4*)s_w1;
    uint4* d2 = (uint4*)s_u1;
    for (int i = tid; i < 2048; i += 256) {
      d0[i] = su0[i];
      d1[i] = sw1[i];
      d2[i] = su1[i];
    }
  }
  __syncthreads();

  const int j = (g << 4) + (lane & 15);
  const int jj = j >> 1;
  const int rA = (lane & 1) << 1;  // even lanes store rows r=0,1; odd r=2,3
  const int rowbase = (mi << 4) + ((lane >> 4) << 2);
  const int arow_off = ((mi << 4) + (lane & 15)) * H_ + ((lane >> 4) << 3);
  const float b1j = b1[j];

  for (int p = 0; p <= S_; ++p) {
    if (wave < 2) {
      if (p < S_) {
        const __hip_bfloat16* ar = h0buf + (((p & 1) ^ 1) << 15) + arow_off;  // h0(p-1)
        bf16x8 xa[32];
#pragma unroll
        for (int kc = 0; kc < 16; ++kc) ldx4_sc(&xa[kc], ar + (kc << 5));
#pragma unroll
        for (int kc = 16; kc < 32; ++kc) ldx4_sc(&xa[kc], ar + (kc << 5));
        f32x4 a0 = {0.f, 0.f, 0.f, 0.f}, a1 = {0.f, 0.f, 0.f, 0.f};
        WAITVM(16);
#pragma unroll
        for (int kc = 0; kc < 16; ++kc) {
          bf16x8 w = *(const bf16x8*)(s_u0 + (((kc << 6) + lane) << 3));
          a0 = __builtin_amdgcn_mfma_f32_16x16x32_bf16(xa[kc], w, a0, 0, 0, 0);
        }
        WAITVM(0);
#pragma unroll
        for (int kc = 16; kc < 32; ++kc) {
          bf16x8 w = *(const bf16x8*)(s_u0 + (((kc << 6) + lane) << 3));
          a1 = __builtin_amdgcn_mfma_f32_16x16x32_bf16(xa[kc], w, a1, 0, 0, 0);
        }
        f32x4 acc = a0 + a1;
        const float* xrow = xw + ((size_t)p << 15);
        float f[4];
#pragma unroll
        for (int r = 0; r < 4; ++r) f[r] = tanhf(acc[r] + xrow[(rowbase + r) * H_ + j]);
        unsigned pk[4];
#pragma unroll
        for (int r = 0; r < 4; ++r) {
          const float o = __shfl_xor(f[r], 1);
          const float lo = (lane & 1) ? o : f[r];
          const float hi = (lane & 1) ? f[r] : o;
          pk[r] = (unsigned)bfbits(lo) | ((unsigned)bfbits(hi) << 16);
        }
        unsigned* h2 = (unsigned*)(h0buf + ((p & 1) << 15));
#pragma unroll
        for (int rr = 0; rr < 2; ++rr) {
          const int r = rA + rr;
          st_swap(h2 + (rowbase + r) * (H_ / 2) + jj, pk[r]);
        }
      }
    } else {
      if (p >= 1) {
        const __hip_bfloat16* ar0 = h0buf + (((p & 1) ^ 1) << 15) + arow_off;  // h0(p-1)
        const __hip_bfloat16* ar1 = h1buf + ((p & 1) << 15) + arow_off;        // h1(p-2)
        bf16x8 pa[32], pb[32];
#pragma unroll
        for (int kc = 0; kc < 16; ++kc) ldx4_sc(&pa[kc], ar0 + (kc << 5));  // A0
#pragma unroll
        for (int kc = 16; kc < 32; ++kc) ldx4_sc(&pa[kc], ar0 + (kc << 5));  // A1
#pragma unroll
        for (int kc = 0; kc < 16; ++kc) ldx4_sc(&pb[kc], ar1 + (kc << 5));  // B0
        f32x4 a0 = {0.f, 0.f, 0.f, 0.f}, a1 = {0.f, 0.f, 0.f, 0.f};
        f32x4 a2 = {0.f, 0.f, 0.f, 0.f}, a3 = {0.f, 0.f, 0.f, 0.f};
        WAITVM(32);  // A0 done
#pragma unroll
        for (int kc = 0; kc < 16; ++kc) {
          bf16x8 w = *(const bf16x8*)(s_w1 + (((kc << 6) + lane) << 3));
          a0 = __builtin_amdgcn_mfma_f32_16x16x32_bf16(pa[kc], w, a0, 0, 0, 0);
        }
#pragma unroll
        for (int kc = 16; kc < 32; ++kc) ldx4_sc(&pb[kc], ar1 + (kc << 5));  // B1
        WAITVM(32);  // A1 done
#pragma unroll
        for (int kc = 16; kc < 32; ++kc) {
          bf16x8 w = *(const bf16x8*)(s_w1 + (((kc << 6) + lane) << 3));
          a1 = __builtin_amdgcn_mfma_f32_16x16x32_bf16(pa[kc], w, a1, 0, 0, 0);
        }
        WAITVM(16);  // B0 done
#pragma unroll
        for (int kc = 0; kc < 16; ++kc) {
          bf16x8 w = *(const bf16x8*)(s_u1 + (((kc << 6) + lane) << 3));
          a2 = __builtin_amdgcn_mfma_f32_16x16x32_bf16(pb[kc], w, a2, 0, 0, 0);
        }
        WAITVM(0);  // B1 done
#pragma unroll
        for (int kc = 16; kc < 32; ++kc) {
          bf16x8 w = *(const bf16x8*)(s_u1 + (((kc << 6) + lane) << 3));
          a3 = __builtin_amdgcn_mfma_f32_16x16x32_bf16(pb[kc], w, a3, 0, 0, 0);
        }
        f32x4 acc = (a0 + a1) + (a2 + a3);
        const int t = p - 1;
        float f[4];
#pragma unroll
        for (int r = 0; r < 4; ++r) f[r] = tanhf(acc[r] + b1j);
        unsigned pk[4];
#pragma unroll
        for (int r = 0; r < 4; ++r) {
          const float o = __shfl_xor(f[r], 1);
          const float lo = (lane & 1) ? o : f[r];
          const float hi = (lane & 1) ? f[r] : o;
          pk[r] = (unsigned)bfbits(lo) | ((unsigned)bfbits(hi) << 16);
        }
        unsigned* h2 = (unsigned*)(h1buf + (((p - 1) & 1) << 15));
        unsigned* Y2 = (unsigned*)Y;
#pragma unroll
        for (int rr = 0; rr < 2; ++rr) {
          const int r = rA + rr;
          const int bb = rowbase + r;
          st_swap(h2 + bb * (H_ / 2) + jj, pk[r]);
          Y2[((size_t)bb * S_ + t) * (H_ / 2) + jj] = pk[r];  // normal cached store
        }
      }
    }
    if (p < S_) {
      // barrier: drain own stores/atomics -> arrive -> spin (relaxed, no fences)
      asm volatile("s_waitcnt vmcnt(0)" ::: "memory");
      __syncthreads();
      if (tid == 0) {
        __hip_atomic_fetch_add(bar, 1u, __ATOMIC_RELAXED, __HIP_MEMORY_SCOPE_AGENT);
        const unsigned tgt = 64u * (unsigned)(p + 1);
        while (__hip_atomic_load(bar, __ATOMIC_RELAXED, __HIP_MEMORY_SCOPE_AGENT) < tgt) {
        }
      }
      __syncthreads();
    }
  }
}

extern "C" void kernel_launch(void* const* d_in, const int* in_sizes, int n_in, void* d_out,
                              int out_size, void* d_ws, size_t ws_size, hipStream_t stream) {
  const int* tokens = (const int*)d_in[0];
  const float* emb = (const float*)d_in[1];
  const float* W0 = (const float*)d_in[2];
  const float* U0 = (const float*)d_in[3];
  const float* b0 = (const float*)d_in[4];
  const float* W1 = (const float*)d_in[5];
  const float* U1 = (const float*)d_in[6];
  const float* b1 = (const float*)d_in[7];
  const float* Wd = (const float*)d_in[8];
  const float* bd = (const float*)d_in[9];
  float* out = (float*)d_out;

  char* ws = (char*)d_ws;
  __hip_bfloat16* Wdt = (__hip_bfloat16*)ws;  ws += (size_t)V_ * H_ * 2;       // 64MB
  __hip_bfloat16* W0t = (__hip_bfloat16*)ws;  ws += (size_t)H_ * E_ * 2;       // 1MB
  __hip_bfloat16* Xg = (__hip_bfloat16*)ws;   ws += (size_t)4096 * E_ * 2;     // 4MB
  __hip_bfloat16* U0f = (__hip_bfloat16*)ws;  ws += (size_t)H_ * H_ * 2;       // 2MB
  __hip_bfloat16* W1f = (__hip_bfloat16*)ws;  ws += (size_t)H_ * H_ * 2;       // 2MB
  __hip_bfloat16* U1f = (__hip_bfloat16*)ws;  ws += (size_t)H_ * H_ * 2;       // 2MB
  float* xw = (float*)ws;                     ws += (size_t)4096 * H_ * 4;     // 16MB
  __hip_bfloat16* h0buf = (__hip_bfloat16*)ws; ws += 2 * B_ * H_ * 2;          // 128KB
  __hip_bfloat16* h1buf = (__hip_bfloat16*)ws; ws += 2 * B_ * H_ * 2;          // 128KB
  __hip_bfloat16* Y = (__hip_bfloat16*)ws;    ws += (size_t)4096 * H_ * 2;     // 8MB
  unsigned* bar = (unsigned*)ws;              ws += 256;

  // prep
  transpose_f32_bf16<<<dim3(V_ / 32, H_ / 32), 256, 0, stream>>>(Wd, Wdt, H_, V_);
  transpose_f32_bf16<<<dim3(H_ / 32, E_ / 32), 256, 0, stream>>>(W0, W0t, E_, H_);
  gather_embed<<<4096, 256, 0, stream>>>(tokens, emb, Xg);
  make_frag_w<<<512, 256, 0, stream>>>(U0, U0f);
  make_frag_w<<<512, 256, 0, stream>>>(W1, W1f);
  make_frag_w<<<512, 256, 0, stream>>>(U1, U1f);
  hipMemsetAsync(h0buf, 0, (size_t)4 * B_ * H_ * 2, stream);  // h0buf + h1buf
  hipMemsetAsync(bar, 0, 256, stream);

  // xw = Xg @ W0 + b0   (M=4096, N=1024, K=512)
  gemm_bf16_tn<<<dim3(H_ / 128, 4096 / 128), 256, 0, stream>>>(Xg, W0t, b0, xw, 4096, H_, E_);

  // recurrence — normal launch; 64 WGs co-resident by construction
  rnn_recur<<<64, 256, 0, stream>>>(U0f, W1f, U1f, xw, b1, h0buf, h1buf, Y, bar);

  // logits = Y @ Wd + bd   (M=4096, N=32000, K=1024)
  gemm_bf16_tn<<<dim3(V_ / 128, 4096 / 128), 256, 0, stream>>>(Y, Wdt, bd, out, 4096, V_, H_);
}